// Round 1
// baseline (1854.670 us; speedup 1.0000x reference)
//
#include <hip/hip_runtime.h>
#include <math.h>

#define F_IN  256
#define F_HID 64
#define F_OUT 40

// ---------------------------------------------------------------- degrees
__global__ void k_deg(const int* __restrict__ dst, float* __restrict__ deg, int E) {
    int i = blockIdx.x * blockDim.x + threadIdx.x;
    if (i < E) atomicAdd(&deg[dst[i]], 1.0f);
}

// deg -> dinv in place (self-loop adds 1, so deg+1 > 0 always)
__global__ void k_dinv(float* __restrict__ deg, int N) {
    int i = blockIdx.x * blockDim.x + threadIdx.x;
    if (i < N) deg[i] = rsqrtf(deg[i] + 1.0f);
}

// ---------------------------------------------------------------- h1 = x @ W1  [N,256]@[256,64]
// 256 threads: 16 nodes/block, each thread computes 4 consecutive features of one node.
__global__ __launch_bounds__(256) void k_mm1(const float* __restrict__ x,
                                             const float* __restrict__ W1,
                                             float* __restrict__ h1, int N) {
    __shared__ float sW[F_IN * F_HID];  // 64 KB
    int tid = threadIdx.x;
    for (int idx = tid; idx < F_IN * F_HID; idx += 256) sW[idx] = W1[idx];
    __syncthreads();

    int node = blockIdx.x * 16 + (tid >> 4);
    int fq = (tid & 15) * 4;
    if (node >= N) return;

    const float4* xr = (const float4*)(x + (size_t)node * F_IN);
    float4 acc = make_float4(0.f, 0.f, 0.f, 0.f);
    #pragma unroll 4
    for (int k4 = 0; k4 < F_IN / 4; ++k4) {
        float4 xv = xr[k4];
        const float* wp = sW + (k4 * 4) * F_HID + fq;
        float4 w0 = *(const float4*)(wp);
        float4 w1 = *(const float4*)(wp + F_HID);
        float4 w2 = *(const float4*)(wp + 2 * F_HID);
        float4 w3 = *(const float4*)(wp + 3 * F_HID);
        acc.x = fmaf(xv.x, w0.x, acc.x); acc.y = fmaf(xv.x, w0.y, acc.y);
        acc.z = fmaf(xv.x, w0.z, acc.z); acc.w = fmaf(xv.x, w0.w, acc.w);
        acc.x = fmaf(xv.y, w1.x, acc.x); acc.y = fmaf(xv.y, w1.y, acc.y);
        acc.z = fmaf(xv.y, w1.z, acc.z); acc.w = fmaf(xv.y, w1.w, acc.w);
        acc.x = fmaf(xv.z, w2.x, acc.x); acc.y = fmaf(xv.z, w2.y, acc.y);
        acc.z = fmaf(xv.z, w2.z, acc.z); acc.w = fmaf(xv.z, w2.w, acc.w);
        acc.x = fmaf(xv.w, w3.x, acc.x); acc.y = fmaf(xv.w, w3.y, acc.y);
        acc.z = fmaf(xv.w, w3.z, acc.z); acc.w = fmaf(xv.w, w3.w, acc.w);
    }
    *(float4*)(h1 + (size_t)node * F_HID + fq) = acc;
}

// ---------------------------------------------------------------- edge scatter, 64-dim (16 thr/edge)
__global__ void k_scat1(const int* __restrict__ src, const int* __restrict__ dst,
                        const float* __restrict__ dinv, const float* __restrict__ h1,
                        float* __restrict__ agg1, int E) {
    int gid = blockIdx.x * blockDim.x + threadIdx.x;
    int e = gid >> 4;
    if (e >= E) return;
    int q = (gid & 15) * 4;
    int s = src[e], d = dst[e];
    float nrm = dinv[s] * dinv[d];
    float4 v = *(const float4*)(h1 + (size_t)s * F_HID + q);
    float* o = agg1 + (size_t)d * F_HID + q;
    atomicAdd(o + 0, v.x * nrm);
    atomicAdd(o + 1, v.y * nrm);
    atomicAdd(o + 2, v.z * nrm);
    atomicAdd(o + 3, v.w * nrm);
}

// self-loop + bias + ReLU, in place on agg1
__global__ void k_relu1(float* __restrict__ agg1, const float* __restrict__ h1,
                        const float* __restrict__ dinv, const float* __restrict__ b1, int N) {
    int i = blockIdx.x * blockDim.x + threadIdx.x;
    if (i >= N * F_HID) return;
    int n = i >> 6, f = i & 63;
    float di = dinv[n];
    float v = agg1[i] + h1[i] * di * di + b1[f];
    agg1[i] = v > 0.f ? v : 0.f;
}

// ---------------------------------------------------------------- h2 = agg1 @ W2  [N,64]@[64,40]
// 320 threads (5 waves): 8 nodes/block, one thread per (node,feature).
__global__ __launch_bounds__(320) void k_mm2(const float* __restrict__ a,
                                             const float* __restrict__ W2,
                                             float* __restrict__ h2, int N) {
    __shared__ float sW[F_HID * F_OUT];  // 10 KB
    int tid = threadIdx.x;
    for (int idx = tid; idx < F_HID * F_OUT; idx += 320) sW[idx] = W2[idx];
    __syncthreads();

    int f = tid % F_OUT, r = tid / F_OUT;
    int node = blockIdx.x * 8 + r;
    if (node >= N) return;
    const float* ar = a + (size_t)node * F_HID;
    float acc = 0.f;
    #pragma unroll 8
    for (int k = 0; k < F_HID; ++k) acc = fmaf(ar[k], sW[k * F_OUT + f], acc);
    h2[(size_t)node * F_OUT + f] = acc;
}

// ---------------------------------------------------------------- edge scatter, 40-dim (10 thr/edge)
__global__ void k_scat2(const int* __restrict__ src, const int* __restrict__ dst,
                        const float* __restrict__ dinv, const float* __restrict__ h2,
                        float* __restrict__ out, int E) {
    int gid = blockIdx.x * blockDim.x + threadIdx.x;
    int e = gid / 10;
    if (e >= E) return;
    int q = (gid % 10) * 4;
    int s = src[e], d = dst[e];
    float nrm = dinv[s] * dinv[d];
    float4 v = *(const float4*)(h2 + (size_t)s * F_OUT + q);
    float* o = out + (size_t)d * F_OUT + q;
    atomicAdd(o + 0, v.x * nrm);
    atomicAdd(o + 1, v.y * nrm);
    atomicAdd(o + 2, v.z * nrm);
    atomicAdd(o + 3, v.w * nrm);
}

// add self-loop contribution into out (b2 cancels under PairNorm mean-subtract),
// and accumulate per-column sums (one atomic per column per block).
__global__ __launch_bounds__(320) void k_colsum(float* __restrict__ out,
                                                const float* __restrict__ h2,
                                                const float* __restrict__ dinv,
                                                float* __restrict__ colsum, int N) {
    __shared__ float part[320];
    int tid = threadIdx.x;
    int f = tid % F_OUT, r = tid / F_OUT;
    float acc = 0.f;
    for (int n0 = blockIdx.x * 8; n0 < N; n0 += gridDim.x * 8) {
        int n = n0 + r;
        if (n < N) {
            size_t idx = (size_t)n * F_OUT + f;
            float di = dinv[n];
            float v = out[idx] + h2[idx] * di * di;
            out[idx] = v;
            acc += v;
        }
    }
    part[tid] = acc;
    __syncthreads();
    if (tid < F_OUT) {
        float s = 0.f;
        #pragma unroll
        for (int j = 0; j < 8; ++j) s += part[tid + F_OUT * j];
        atomicAdd(&colsum[tid], s);
    }
}

// PairNorm-SI + log_softmax, in place on out. One thread per node.
__global__ __launch_bounds__(128) void k_final(float* __restrict__ out,
                                               const float* __restrict__ colsum, int N) {
    __shared__ float sMean[F_OUT];
    if (threadIdx.x < F_OUT) sMean[threadIdx.x] = colsum[threadIdx.x] * (1.0f / (float)N);
    __syncthreads();
    int n = blockIdx.x * blockDim.x + threadIdx.x;
    if (n >= N) return;
    float* row = out + (size_t)n * F_OUT;
    float v[F_OUT];
    float ss = 0.f;
    #pragma unroll
    for (int f = 0; f < F_OUT; ++f) {
        float t = row[f] - sMean[f];
        v[f] = t;
        ss += t * t;
    }
    float scale = 1.0f / sqrtf(ss + 1e-6f);
    float m = -1e30f;
    #pragma unroll
    for (int f = 0; f < F_OUT; ++f) {
        float y = v[f] * scale;
        v[f] = y;
        m = fmaxf(m, y);
    }
    float sum = 0.f;
    #pragma unroll
    for (int f = 0; f < F_OUT; ++f) sum += expf(v[f] - m);
    float lse = logf(sum);
    #pragma unroll
    for (int f = 0; f < F_OUT; ++f) row[f] = v[f] - m - lse;
}

extern "C" void kernel_launch(void* const* d_in, const int* in_sizes, int n_in,
                              void* d_out, int out_size, void* d_ws, size_t ws_size,
                              hipStream_t stream) {
    const float* x  = (const float*)d_in[0];
    const int*   ei = (const int*)d_in[1];   // per harness: integer inputs arrive as int32
    const float* W1 = (const float*)d_in[2];
    const float* b1 = (const float*)d_in[3];
    const float* W2 = (const float*)d_in[4];
    // b2 = d_in[5] unused: cancels under PairNorm mean subtraction.
    float* out = (float*)d_out;

    int N = in_sizes[0] / F_IN;
    int E = in_sizes[1] / 2;
    const int* src = ei;
    const int* dst = ei + E;

    // workspace layout (floats): [deg/dinv N][agg1 64N][colsum 64][h1 64N][h2 40N]
    float* ws = (float*)d_ws;
    float* dinv   = ws;
    float* agg1   = ws + N;
    float* colsum = ws + (size_t)65 * N;
    float* h1     = colsum + 64;
    float* h2     = h1 + (size_t)64 * N;

    // zero: deg + agg1 + colsum (contiguous), and d_out (agg2 accumulates there)
    hipMemsetAsync(d_ws, 0, ((size_t)65 * N + 64) * sizeof(float), stream);
    hipMemsetAsync(d_out, 0, (size_t)out_size * sizeof(float), stream);

    k_deg<<<(E + 255) / 256, 256, 0, stream>>>(dst, dinv, E);
    k_dinv<<<(N + 255) / 256, 256, 0, stream>>>(dinv, N);
    k_mm1<<<(N + 15) / 16, 256, 0, stream>>>(x, W1, h1, N);
    k_scat1<<<(int)(((long long)E * 16 + 255) / 256), 256, 0, stream>>>(src, dst, dinv, h1, agg1, E);
    k_relu1<<<(int)(((long long)N * 64 + 255) / 256), 256, 0, stream>>>(agg1, h1, dinv, b1, N);
    k_mm2<<<(N + 7) / 8, 320, 0, stream>>>(agg1, W2, h2, N);
    k_scat2<<<(int)(((long long)E * 10 + 255) / 256), 256, 0, stream>>>(src, dst, dinv, h2, out, E);
    k_colsum<<<1024, 320, 0, stream>>>(out, h2, dinv, colsum, N);
    k_final<<<(N + 127) / 128, 128, 0, stream>>>(out, colsum, N);
}

// Round 2
// 637.968 us; speedup vs baseline: 2.9072x; 2.9072x over previous
//
#include <hip/hip_runtime.h>
#include <math.h>

#define F_IN  256
#define F_HID 64
#define F_OUT 40

// ---------------------------------------------------------------- degree histogram (int)
__global__ void k_deg(const int* __restrict__ dst, unsigned* __restrict__ degc, int E) {
    int i = blockIdx.x * blockDim.x + threadIdx.x;
    if (i < E) atomicAdd(&degc[dst[i]], 1u);
}

// ---------------------------------------------------------------- 3-phase exclusive scan of degc -> rowptr
__global__ __launch_bounds__(256) void k_scanA(const unsigned* __restrict__ degc,
                                               unsigned* __restrict__ exscan,
                                               unsigned* __restrict__ bsum, int N) {
    __shared__ unsigned s[256];
    int tid = threadIdx.x;
    int i = blockIdx.x * 256 + tid;
    unsigned v = (i < N) ? degc[i] : 0u;
    s[tid] = v;
    __syncthreads();
    for (int off = 1; off < 256; off <<= 1) {
        unsigned t = (tid >= off) ? s[tid - off] : 0u;
        __syncthreads();
        s[tid] += t;
        __syncthreads();
    }
    if (i < N) exscan[i] = s[tid] - v;
    if (tid == 255) bsum[blockIdx.x] = s[255];
}

__global__ __launch_bounds__(512) void k_scanB(unsigned* __restrict__ bsum, int nb) {
    __shared__ unsigned s[512];
    int tid = threadIdx.x;
    unsigned v = (tid < nb) ? bsum[tid] : 0u;
    s[tid] = v;
    __syncthreads();
    for (int off = 1; off < 512; off <<= 1) {
        unsigned t = (tid >= off) ? s[tid - off] : 0u;
        __syncthreads();
        s[tid] += t;
        __syncthreads();
    }
    if (tid < nb) bsum[tid] = s[tid] - v;  // exclusive
}

__global__ void k_scanC(const unsigned* __restrict__ degc, const unsigned* __restrict__ exscan,
                        const unsigned* __restrict__ bsum, unsigned* __restrict__ rowptr,
                        float* __restrict__ dinv, int N, int E) {
    int i = blockIdx.x * blockDim.x + threadIdx.x;
    if (i < N) {
        rowptr[i] = exscan[i] + bsum[i >> 8];
        dinv[i] = rsqrtf((float)degc[i] + 1.0f);  // +1 self loop
        if (i == 0) rowptr[N] = (unsigned)E;
    }
}

// bucket fill: col[rowptr[d] + cursor[d]++] = src
__global__ void k_fill(const int* __restrict__ src, const int* __restrict__ dst,
                       const unsigned* __restrict__ rowptr, unsigned* __restrict__ cursor,
                       unsigned* __restrict__ col, int E) {
    int e = blockIdx.x * blockDim.x + threadIdx.x;
    if (e >= E) return;
    int d = dst[e];
    unsigned p = atomicAdd(&cursor[d], 1u);
    col[rowptr[d] + p] = (unsigned)src[e];
}

// ---------------------------------------------------------------- h1 = x @ W1  [N,256]@[256,64]
__global__ __launch_bounds__(256) void k_mm1(const float* __restrict__ x,
                                             const float* __restrict__ W1,
                                             float* __restrict__ h1, int N) {
    __shared__ float sW[F_IN * F_HID];  // 64 KB
    int tid = threadIdx.x;
    for (int idx = tid; idx < F_IN * F_HID; idx += 256) sW[idx] = W1[idx];
    __syncthreads();

    int node = blockIdx.x * 16 + (tid >> 4);
    int fq = (tid & 15) * 4;
    if (node >= N) return;

    const float4* xr = (const float4*)(x + (size_t)node * F_IN);
    float4 acc = make_float4(0.f, 0.f, 0.f, 0.f);
    #pragma unroll 4
    for (int k4 = 0; k4 < F_IN / 4; ++k4) {
        float4 xv = xr[k4];
        const float* wp = sW + (k4 * 4) * F_HID + fq;
        float4 w0 = *(const float4*)(wp);
        float4 w1 = *(const float4*)(wp + F_HID);
        float4 w2 = *(const float4*)(wp + 2 * F_HID);
        float4 w3 = *(const float4*)(wp + 3 * F_HID);
        acc.x = fmaf(xv.x, w0.x, acc.x); acc.y = fmaf(xv.x, w0.y, acc.y);
        acc.z = fmaf(xv.x, w0.z, acc.z); acc.w = fmaf(xv.x, w0.w, acc.w);
        acc.x = fmaf(xv.y, w1.x, acc.x); acc.y = fmaf(xv.y, w1.y, acc.y);
        acc.z = fmaf(xv.y, w1.z, acc.z); acc.w = fmaf(xv.y, w1.w, acc.w);
        acc.x = fmaf(xv.z, w2.x, acc.x); acc.y = fmaf(xv.z, w2.y, acc.y);
        acc.z = fmaf(xv.z, w2.z, acc.z); acc.w = fmaf(xv.z, w2.w, acc.w);
        acc.x = fmaf(xv.w, w3.x, acc.x); acc.y = fmaf(xv.w, w3.y, acc.y);
        acc.z = fmaf(xv.w, w3.z, acc.z); acc.w = fmaf(xv.w, w3.w, acc.w);
    }
    *(float4*)(h1 + (size_t)node * F_HID + fq) = acc;
}

// ---------------------------------------------------------------- gather-aggregate layer 1
// one wave per node, lane = feature; fused self-loop + bias + ReLU
__global__ __launch_bounds__(256) void k_agg1(const unsigned* __restrict__ rowptr,
                                              const unsigned* __restrict__ col,
                                              const float* __restrict__ dinv,
                                              const float* __restrict__ h1,
                                              const float* __restrict__ b1,
                                              float* __restrict__ agg1, int N) {
    int lane = threadIdx.x & 63;
    int node = blockIdx.x * 4 + (threadIdx.x >> 6);
    if (node >= N) return;
    float din = dinv[node];
    unsigned r0 = rowptr[node], r1 = rowptr[node + 1];
    float acc = h1[(size_t)node * F_HID + lane] * din * din;  // self loop
    for (unsigned e = r0; e < r1; ++e) {
        unsigned s = col[e];
        float nm = dinv[s] * din;
        acc = fmaf(h1[(size_t)s * F_HID + lane], nm, acc);
    }
    float v = acc + b1[lane];
    agg1[(size_t)node * F_HID + lane] = v > 0.f ? v : 0.f;
}

// ---------------------------------------------------------------- h2 = agg1 @ W2  [N,64]@[64,40]
__global__ __launch_bounds__(320) void k_mm2(const float* __restrict__ a,
                                             const float* __restrict__ W2,
                                             float* __restrict__ h2, int N) {
    __shared__ float sW[F_HID * F_OUT];
    int tid = threadIdx.x;
    for (int idx = tid; idx < F_HID * F_OUT; idx += 320) sW[idx] = W2[idx];
    __syncthreads();

    int f = tid % F_OUT, r = tid / F_OUT;
    int node = blockIdx.x * 8 + r;
    if (node >= N) return;
    const float* ar = a + (size_t)node * F_HID;
    float acc = 0.f;
    #pragma unroll 8
    for (int k = 0; k < F_HID; ++k) acc = fmaf(ar[k], sW[k * F_OUT + f], acc);
    h2[(size_t)node * F_OUT + f] = acc;
}

// ---------------------------------------------------------------- gather-aggregate layer 2
// one wave per node (grid-stride), lanes 0..39 = features; fused self-loop + column sums
// (b2 cancels under PairNorm mean subtraction)
__global__ __launch_bounds__(256) void k_agg2(const unsigned* __restrict__ rowptr,
                                              const unsigned* __restrict__ col,
                                              const float* __restrict__ dinv,
                                              const float* __restrict__ h2,
                                              float* __restrict__ out,
                                              float* __restrict__ colsum, int N) {
    __shared__ float part[256];
    int lane = threadIdx.x & 63;
    int wid = threadIdx.x >> 6;
    float cacc = 0.f;
    if (lane < F_OUT) {
        for (int node = blockIdx.x * 4 + wid; node < N; node += gridDim.x * 4) {
            float din = dinv[node];
            unsigned r0 = rowptr[node], r1 = rowptr[node + 1];
            float acc = h2[(size_t)node * F_OUT + lane] * din * din;
            for (unsigned e = r0; e < r1; ++e) {
                unsigned s = col[e];
                acc = fmaf(h2[(size_t)s * F_OUT + lane], dinv[s] * din, acc);
            }
            out[(size_t)node * F_OUT + lane] = acc;
            cacc += acc;
        }
    }
    part[threadIdx.x] = cacc;
    __syncthreads();
    if (threadIdx.x < F_OUT) {
        float s = part[threadIdx.x] + part[64 + threadIdx.x] + part[128 + threadIdx.x] + part[192 + threadIdx.x];
        atomicAdd(&colsum[threadIdx.x], s);
    }
}

// ---------------------------------------------------------------- PairNorm-SI + log_softmax
__global__ __launch_bounds__(128) void k_final(float* __restrict__ out,
                                               const float* __restrict__ colsum, int N) {
    __shared__ float sMean[F_OUT];
    if (threadIdx.x < F_OUT) sMean[threadIdx.x] = colsum[threadIdx.x] * (1.0f / (float)N);
    __syncthreads();
    int n = blockIdx.x * blockDim.x + threadIdx.x;
    if (n >= N) return;
    float* row = out + (size_t)n * F_OUT;
    float v[F_OUT];
    float ss = 0.f;
    #pragma unroll
    for (int f = 0; f < F_OUT; ++f) {
        float t = row[f] - sMean[f];
        v[f] = t;
        ss += t * t;
    }
    float scale = 1.0f / sqrtf(ss + 1e-6f);
    float m = -1e30f;
    #pragma unroll
    for (int f = 0; f < F_OUT; ++f) {
        float y = v[f] * scale;
        v[f] = y;
        m = fmaxf(m, y);
    }
    float sum = 0.f;
    #pragma unroll
    for (int f = 0; f < F_OUT; ++f) sum += expf(v[f] - m);
    float lse = logf(sum);
    #pragma unroll
    for (int f = 0; f < F_OUT; ++f) row[f] = v[f] - m - lse;
}

extern "C" void kernel_launch(void* const* d_in, const int* in_sizes, int n_in,
                              void* d_out, int out_size, void* d_ws, size_t ws_size,
                              hipStream_t stream) {
    const float* x  = (const float*)d_in[0];
    const int*   ei = (const int*)d_in[1];   // int32 per harness (verified R1)
    const float* W1 = (const float*)d_in[2];
    const float* b1 = (const float*)d_in[3];
    const float* W2 = (const float*)d_in[4];
    // b2 unused: cancels under PairNorm mean subtraction.
    float* out = (float*)d_out;

    int N = in_sizes[0] / F_IN;
    int E = in_sizes[1] / 2;
    const int* src = ei;
    const int* dst = ei + E;

    // workspace layout (4-byte words):
    // [degc N][cursor N][colsum 64][rowptr N+1][col E][dinv N][h1 64N][agg1 64N][h2 40N]
    // scan temporaries exscan(N)+bsum(512) alias the h2 region (h2 written later).
    unsigned* degc   = (unsigned*)d_ws;
    unsigned* cursor = degc + N;
    float*    colsum = (float*)(cursor + N);
    unsigned* rowptr = (unsigned*)(colsum + 64);
    unsigned* col    = rowptr + N + 1;
    float*    dinv   = (float*)(col + E);
    float*    h1     = dinv + N;
    float*    agg1   = h1 + (size_t)64 * N;
    float*    h2     = agg1 + (size_t)64 * N;
    unsigned* exscan = (unsigned*)h2;        // alias, used only during CSR build
    unsigned* bsum   = exscan + N;

    // zero degc+cursor+colsum (contiguous)
    hipMemsetAsync(d_ws, 0, ((size_t)2 * N + 64) * sizeof(float), stream);

    int nA = (N + 255) / 256;  // 391 for N=100000, must be <= 512 for k_scanB
    k_deg<<<(E + 255) / 256, 256, 0, stream>>>(dst, degc, E);
    k_scanA<<<nA, 256, 0, stream>>>(degc, exscan, bsum, N);
    k_scanB<<<1, 512, 0, stream>>>(bsum, nA);
    k_scanC<<<nA, 256, 0, stream>>>(degc, exscan, bsum, rowptr, dinv, N, E);
    k_fill<<<(E + 255) / 256, 256, 0, stream>>>(src, dst, rowptr, cursor, col, E);
    k_mm1<<<(N + 15) / 16, 256, 0, stream>>>(x, W1, h1, N);
    k_agg1<<<(N + 3) / 4, 256, 0, stream>>>(rowptr, col, dinv, h1, b1, agg1, N);
    k_mm2<<<(N + 7) / 8, 320, 0, stream>>>(agg1, W2, h2, N);
    k_agg2<<<2048, 256, 0, stream>>>(rowptr, col, dinv, h2, out, colsum, N);
    k_final<<<(N + 127) / 128, 128, 0, stream>>>(out, colsum, N);
}

// Round 3
// 493.812 us; speedup vs baseline: 3.7558x; 1.2919x over previous
//
#include <hip/hip_runtime.h>
#include <math.h>

#define F_IN  256
#define F_HID 64
#define F_OUT 40

// ---------------------------------------------------------------- degree histogram (int)
__global__ void k_deg(const int* __restrict__ dst, unsigned* __restrict__ degc, int E) {
    int i = blockIdx.x * blockDim.x + threadIdx.x;
    if (i < E) atomicAdd(&degc[dst[i]], 1u);
}

// ---------------------------------------------------------------- 3-phase exclusive scan of degc -> rowptr
__global__ __launch_bounds__(256) void k_scanA(const unsigned* __restrict__ degc,
                                               unsigned* __restrict__ exscan,
                                               unsigned* __restrict__ bsum, int N) {
    __shared__ unsigned s[256];
    int tid = threadIdx.x;
    int i = blockIdx.x * 256 + tid;
    unsigned v = (i < N) ? degc[i] : 0u;
    s[tid] = v;
    __syncthreads();
    for (int off = 1; off < 256; off <<= 1) {
        unsigned t = (tid >= off) ? s[tid - off] : 0u;
        __syncthreads();
        s[tid] += t;
        __syncthreads();
    }
    if (i < N) exscan[i] = s[tid] - v;
    if (tid == 255) bsum[blockIdx.x] = s[255];
}

__global__ __launch_bounds__(512) void k_scanB(unsigned* __restrict__ bsum, int nb) {
    __shared__ unsigned s[512];
    int tid = threadIdx.x;
    unsigned v = (tid < nb) ? bsum[tid] : 0u;
    s[tid] = v;
    __syncthreads();
    for (int off = 1; off < 512; off <<= 1) {
        unsigned t = (tid >= off) ? s[tid - off] : 0u;
        __syncthreads();
        s[tid] += t;
        __syncthreads();
    }
    if (tid < nb) bsum[tid] = s[tid] - v;  // exclusive
}

__global__ void k_scanC(const unsigned* __restrict__ degc, const unsigned* __restrict__ exscan,
                        const unsigned* __restrict__ bsum, unsigned* __restrict__ rowptr,
                        float* __restrict__ dinv, int N, int E) {
    int i = blockIdx.x * blockDim.x + threadIdx.x;
    if (i < N) {
        rowptr[i] = exscan[i] + bsum[i >> 8];
        dinv[i] = rsqrtf((float)degc[i] + 1.0f);  // +1 self loop
        if (i == 0) rowptr[N] = (unsigned)E;
    }
}

// bucket fill: col[rowptr[d] + cursor[d]++] = src
__global__ void k_fill(const int* __restrict__ src, const int* __restrict__ dst,
                       const unsigned* __restrict__ rowptr, unsigned* __restrict__ cursor,
                       unsigned* __restrict__ col, int E) {
    int e = blockIdx.x * blockDim.x + threadIdx.x;
    if (e >= E) return;
    int d = dst[e];
    unsigned p = atomicAdd(&cursor[d], 1u);
    col[rowptr[d] + p] = (unsigned)src[e];
}

// ---------------------------------------------------------------- h1 = x @ W1  [N,256]@[256,64]
// 64x64 output tile per block, K-chunks of 32. sX transposed (k-major) so the
// compute loop is 2x ds_read_b128 + 16 FMA per k. LDS 16.9 KB -> ~6 blocks/CU.
#define MM1_KC 32
#define MM1_XP 68   // padded row: 16B-aligned float4 reads, conflict-free
__global__ __launch_bounds__(256) void k_mm1(const float* __restrict__ x,
                                             const float* __restrict__ W1,
                                             float* __restrict__ h1, int N) {
    __shared__ float sX[MM1_KC][MM1_XP];  // [k][node]
    __shared__ float sW[MM1_KC][F_HID];   // [k][feat]
    int tid = threadIdx.x;
    int nbase = blockIdx.x * 64;
    int n0 = (tid & 15) * 4;   // node offset within tile
    int f0 = (tid >> 4) * 4;   // feature offset

    float acc[4][4];
    #pragma unroll
    for (int i = 0; i < 4; ++i)
        #pragma unroll
        for (int j = 0; j < 4; ++j) acc[i][j] = 0.f;

    for (int k0 = 0; k0 < F_IN; k0 += MM1_KC) {
        // stage x chunk transposed: 64 nodes x 32 k = 512 float4, 2 per thread
        #pragma unroll
        for (int q = tid; q < 512; q += 256) {
            int row = q >> 3;          // node within tile
            int c4  = q & 7;           // float4 within the 32-k chunk
            int node = nbase + row;
            float4 v = (node < N) ? *(const float4*)(x + (size_t)node * F_IN + k0 + c4 * 4)
                                  : make_float4(0.f, 0.f, 0.f, 0.f);
            sX[c4 * 4 + 0][row] = v.x;
            sX[c4 * 4 + 1][row] = v.y;
            sX[c4 * 4 + 2][row] = v.z;
            sX[c4 * 4 + 3][row] = v.w;
        }
        // stage W chunk: 32 k x 64 f = 512 float4, 2 per thread
        #pragma unroll
        for (int q = tid; q < 512; q += 256) {
            int r  = q >> 4;
            int c4 = q & 15;
            *(float4*)&sW[r][c4 * 4] = *(const float4*)(W1 + (size_t)(k0 + r) * F_HID + c4 * 4);
        }
        __syncthreads();

        #pragma unroll
        for (int k = 0; k < MM1_KC; ++k) {
            float4 xv = *(const float4*)&sX[k][n0];
            float4 wv = *(const float4*)&sW[k][f0];
            acc[0][0] = fmaf(xv.x, wv.x, acc[0][0]); acc[0][1] = fmaf(xv.x, wv.y, acc[0][1]);
            acc[0][2] = fmaf(xv.x, wv.z, acc[0][2]); acc[0][3] = fmaf(xv.x, wv.w, acc[0][3]);
            acc[1][0] = fmaf(xv.y, wv.x, acc[1][0]); acc[1][1] = fmaf(xv.y, wv.y, acc[1][1]);
            acc[1][2] = fmaf(xv.y, wv.z, acc[1][2]); acc[1][3] = fmaf(xv.y, wv.w, acc[1][3]);
            acc[2][0] = fmaf(xv.z, wv.x, acc[2][0]); acc[2][1] = fmaf(xv.z, wv.y, acc[2][1]);
            acc[2][2] = fmaf(xv.z, wv.z, acc[2][2]); acc[2][3] = fmaf(xv.z, wv.w, acc[2][3]);
            acc[3][0] = fmaf(xv.w, wv.x, acc[3][0]); acc[3][1] = fmaf(xv.w, wv.y, acc[3][1]);
            acc[3][2] = fmaf(xv.w, wv.z, acc[3][2]); acc[3][3] = fmaf(xv.w, wv.w, acc[3][3]);
        }
        __syncthreads();
    }

    #pragma unroll
    for (int i = 0; i < 4; ++i) {
        int node = nbase + n0 + i;
        if (node < N)
            *(float4*)(h1 + (size_t)node * F_HID + f0) =
                make_float4(acc[i][0], acc[i][1], acc[i][2], acc[i][3]);
    }
}

// ---------------------------------------------------------------- gather-aggregate layer 1
// one wave per node, lane = feature; fused self-loop + bias + ReLU; 2-wide edge unroll
__global__ __launch_bounds__(256) void k_agg1(const unsigned* __restrict__ rowptr,
                                              const unsigned* __restrict__ col,
                                              const float* __restrict__ dinv,
                                              const float* __restrict__ h1,
                                              const float* __restrict__ b1,
                                              float* __restrict__ agg1, int N) {
    int lane = threadIdx.x & 63;
    int node = blockIdx.x * 4 + (threadIdx.x >> 6);
    if (node >= N) return;
    float din = dinv[node];
    unsigned r0 = rowptr[node], r1 = rowptr[node + 1];
    float acc = h1[(size_t)node * F_HID + lane] * din * din;  // self loop
    unsigned e = r0;
    for (; e + 2 <= r1; e += 2) {
        unsigned s0 = col[e], s1 = col[e + 1];
        float w0 = dinv[s0] * din, w1 = dinv[s1] * din;
        float v0 = h1[(size_t)s0 * F_HID + lane];
        float v1 = h1[(size_t)s1 * F_HID + lane];
        acc = fmaf(v0, w0, acc);
        acc = fmaf(v1, w1, acc);
    }
    if (e < r1) {
        unsigned s = col[e];
        acc = fmaf(h1[(size_t)s * F_HID + lane], dinv[s] * din, acc);
    }
    float v = acc + b1[lane];
    agg1[(size_t)node * F_HID + lane] = v > 0.f ? v : 0.f;
}

// ---------------------------------------------------------------- h2 = agg1 @ W2  [N,64]@[64,40]
__global__ __launch_bounds__(320) void k_mm2(const float* __restrict__ a,
                                             const float* __restrict__ W2,
                                             float* __restrict__ h2, int N) {
    __shared__ float sW[F_HID * F_OUT];
    int tid = threadIdx.x;
    for (int idx = tid; idx < F_HID * F_OUT; idx += 320) sW[idx] = W2[idx];
    __syncthreads();

    int f = tid % F_OUT, r = tid / F_OUT;
    int node = blockIdx.x * 8 + r;
    if (node >= N) return;
    const float* ar = a + (size_t)node * F_HID;
    float acc = 0.f;
    #pragma unroll 8
    for (int k = 0; k < F_HID; ++k) acc = fmaf(ar[k], sW[k * F_OUT + f], acc);
    h2[(size_t)node * F_OUT + f] = acc;
}

// ---------------------------------------------------------------- gather-aggregate layer 2
// one wave per node (grid-stride), lanes 0..39 = features; fused self-loop + column sums
// (b2 cancels under PairNorm mean subtraction)
__global__ __launch_bounds__(256) void k_agg2(const unsigned* __restrict__ rowptr,
                                              const unsigned* __restrict__ col,
                                              const float* __restrict__ dinv,
                                              const float* __restrict__ h2,
                                              float* __restrict__ out,
                                              float* __restrict__ colsum, int N) {
    __shared__ float part[256];
    int lane = threadIdx.x & 63;
    int wid = threadIdx.x >> 6;
    float cacc = 0.f;
    if (lane < F_OUT) {
        for (int node = blockIdx.x * 4 + wid; node < N; node += gridDim.x * 4) {
            float din = dinv[node];
            unsigned r0 = rowptr[node], r1 = rowptr[node + 1];
            float acc = h2[(size_t)node * F_OUT + lane] * din * din;
            unsigned e = r0;
            for (; e + 2 <= r1; e += 2) {
                unsigned s0 = col[e], s1 = col[e + 1];
                float w0 = dinv[s0] * din, w1 = dinv[s1] * din;
                float v0 = h2[(size_t)s0 * F_OUT + lane];
                float v1 = h2[(size_t)s1 * F_OUT + lane];
                acc = fmaf(v0, w0, acc);
                acc = fmaf(v1, w1, acc);
            }
            if (e < r1) {
                unsigned s = col[e];
                acc = fmaf(h2[(size_t)s * F_OUT + lane], dinv[s] * din, acc);
            }
            out[(size_t)node * F_OUT + lane] = acc;
            cacc += acc;
        }
    }
    part[threadIdx.x] = cacc;
    __syncthreads();
    if (threadIdx.x < F_OUT) {
        float s = part[threadIdx.x] + part[64 + threadIdx.x] + part[128 + threadIdx.x] + part[192 + threadIdx.x];
        atomicAdd(&colsum[threadIdx.x], s);
    }
}

// ---------------------------------------------------------------- PairNorm-SI + log_softmax
__global__ __launch_bounds__(128) void k_final(float* __restrict__ out,
                                               const float* __restrict__ colsum, int N) {
    __shared__ float sMean[F_OUT];
    if (threadIdx.x < F_OUT) sMean[threadIdx.x] = colsum[threadIdx.x] * (1.0f / (float)N);
    __syncthreads();
    int n = blockIdx.x * blockDim.x + threadIdx.x;
    if (n >= N) return;
    float* row = out + (size_t)n * F_OUT;
    float v[F_OUT];
    float ss = 0.f;
    #pragma unroll
    for (int f = 0; f < F_OUT; ++f) {
        float t = row[f] - sMean[f];
        v[f] = t;
        ss += t * t;
    }
    float scale = 1.0f / sqrtf(ss + 1e-6f);
    float m = -1e30f;
    #pragma unroll
    for (int f = 0; f < F_OUT; ++f) {
        float y = v[f] * scale;
        v[f] = y;
        m = fmaxf(m, y);
    }
    float sum = 0.f;
    #pragma unroll
    for (int f = 0; f < F_OUT; ++f) sum += expf(v[f] - m);
    float lse = logf(sum);
    #pragma unroll
    for (int f = 0; f < F_OUT; ++f) row[f] = v[f] - m - lse;
}

extern "C" void kernel_launch(void* const* d_in, const int* in_sizes, int n_in,
                              void* d_out, int out_size, void* d_ws, size_t ws_size,
                              hipStream_t stream) {
    const float* x  = (const float*)d_in[0];
    const int*   ei = (const int*)d_in[1];   // int32 per harness (verified R1)
    const float* W1 = (const float*)d_in[2];
    const float* b1 = (const float*)d_in[3];
    const float* W2 = (const float*)d_in[4];
    // b2 unused: cancels under PairNorm mean subtraction.
    float* out = (float*)d_out;

    int N = in_sizes[0] / F_IN;
    int E = in_sizes[1] / 2;
    const int* src = ei;
    const int* dst = ei + E;

    // workspace layout (4-byte words):
    // [degc N][cursor N][colsum 64][rowptr N+1][col E][dinv N][h1 64N][agg1 64N][h2 40N]
    // scan temporaries exscan(N)+bsum(512) alias the h2 region (h2 written later).
    unsigned* degc   = (unsigned*)d_ws;
    unsigned* cursor = degc + N;
    float*    colsum = (float*)(cursor + N);
    unsigned* rowptr = (unsigned*)(colsum + 64);
    unsigned* col    = rowptr + N + 1;
    float*    dinv   = (float*)(col + E);
    float*    h1     = dinv + N;
    float*    agg1   = h1 + (size_t)64 * N;
    float*    h2     = agg1 + (size_t)64 * N;
    unsigned* exscan = (unsigned*)h2;        // alias, used only during CSR build
    unsigned* bsum   = exscan + N;

    // zero degc+cursor+colsum (contiguous)
    hipMemsetAsync(d_ws, 0, ((size_t)2 * N + 64) * sizeof(float), stream);

    int nA = (N + 255) / 256;  // 391 for N=100000, must be <= 512 for k_scanB
    k_deg<<<(E + 255) / 256, 256, 0, stream>>>(dst, degc, E);
    k_scanA<<<nA, 256, 0, stream>>>(degc, exscan, bsum, N);
    k_scanB<<<1, 512, 0, stream>>>(bsum, nA);
    k_scanC<<<nA, 256, 0, stream>>>(degc, exscan, bsum, rowptr, dinv, N, E);
    k_fill<<<(E + 255) / 256, 256, 0, stream>>>(src, dst, rowptr, cursor, col, E);
    k_mm1<<<(N + 63) / 64, 256, 0, stream>>>(x, W1, h1, N);
    k_agg1<<<(N + 3) / 4, 256, 0, stream>>>(rowptr, col, dinv, h1, b1, agg1, N);
    k_mm2<<<(N + 7) / 8, 320, 0, stream>>>(agg1, W2, h2, N);
    k_agg2<<<2048, 256, 0, stream>>>(rowptr, col, dinv, h2, out, colsum, N);
    k_final<<<(N + 127) / 128, 128, 0, stream>>>(out, colsum, N);
}

// Round 4
// 460.762 us; speedup vs baseline: 4.0252x; 1.0717x over previous
//
#include <hip/hip_runtime.h>
#include <hip/hip_fp16.h>
#include <math.h>

#define F_IN  256
#define F_HID 64
#define F_OUT 40
#define HS2_LD 64   // padded fp16 row stride for hs2: 64*2B = one 128B line

// ---------------------------------------------------------------- degree histogram (int)
__global__ void k_deg(const int* __restrict__ dst, unsigned* __restrict__ degc, int E) {
    int i = blockIdx.x * blockDim.x + threadIdx.x;
    if (i < E) atomicAdd(&degc[dst[i]], 1u);
}

// ---------------------------------------------------------------- 3-phase exclusive scan of degc -> rowptr
__global__ __launch_bounds__(256) void k_scanA(const unsigned* __restrict__ degc,
                                               unsigned* __restrict__ exscan,
                                               unsigned* __restrict__ bsum, int N) {
    __shared__ unsigned s[256];
    int tid = threadIdx.x;
    int i = blockIdx.x * 256 + tid;
    unsigned v = (i < N) ? degc[i] : 0u;
    s[tid] = v;
    __syncthreads();
    for (int off = 1; off < 256; off <<= 1) {
        unsigned t = (tid >= off) ? s[tid - off] : 0u;
        __syncthreads();
        s[tid] += t;
        __syncthreads();
    }
    if (i < N) exscan[i] = s[tid] - v;
    if (tid == 255) bsum[blockIdx.x] = s[255];
}

__global__ __launch_bounds__(512) void k_scanB(unsigned* __restrict__ bsum, int nb) {
    __shared__ unsigned s[512];
    int tid = threadIdx.x;
    unsigned v = (tid < nb) ? bsum[tid] : 0u;
    s[tid] = v;
    __syncthreads();
    for (int off = 1; off < 512; off <<= 1) {
        unsigned t = (tid >= off) ? s[tid - off] : 0u;
        __syncthreads();
        s[tid] += t;
        __syncthreads();
    }
    if (tid < nb) bsum[tid] = s[tid] - v;  // exclusive
}

__global__ void k_scanC(const unsigned* __restrict__ degc, const unsigned* __restrict__ exscan,
                        const unsigned* __restrict__ bsum, unsigned* __restrict__ rowptr,
                        float* __restrict__ dinv, int N, int E) {
    int i = blockIdx.x * blockDim.x + threadIdx.x;
    if (i < N) {
        rowptr[i] = exscan[i] + bsum[i >> 8];
        dinv[i] = rsqrtf((float)degc[i] + 1.0f);  // +1 self loop
        if (i == 0) rowptr[N] = (unsigned)E;
    }
}

// bucket fill: col[rowptr[d] + cursor[d]++] = src
__global__ void k_fill(const int* __restrict__ src, const int* __restrict__ dst,
                       const unsigned* __restrict__ rowptr, unsigned* __restrict__ cursor,
                       unsigned* __restrict__ col, int E) {
    int e = blockIdx.x * blockDim.x + threadIdx.x;
    if (e >= E) return;
    int d = dst[e];
    unsigned p = atomicAdd(&cursor[d], 1u);
    col[rowptr[d] + p] = (unsigned)src[e];
}

// ---------------------------------------------------------------- hs1 = (x @ W1) * dinv[node], fp16
// 64x64 output tile per block, K-chunks of 32, transposed x in LDS.
#define MM1_KC 32
#define MM1_XP 68
__global__ __launch_bounds__(256) void k_mm1(const float* __restrict__ x,
                                             const float* __restrict__ W1,
                                             const float* __restrict__ dinv,
                                             __half* __restrict__ hs1, int N) {
    __shared__ float sX[MM1_KC][MM1_XP];  // [k][node]
    __shared__ float sW[MM1_KC][F_HID];   // [k][feat]
    int tid = threadIdx.x;
    int nbase = blockIdx.x * 64;
    int n0 = (tid & 15) * 4;
    int f0 = (tid >> 4) * 4;

    float acc[4][4];
    #pragma unroll
    for (int i = 0; i < 4; ++i)
        #pragma unroll
        for (int j = 0; j < 4; ++j) acc[i][j] = 0.f;

    for (int k0 = 0; k0 < F_IN; k0 += MM1_KC) {
        #pragma unroll
        for (int q = tid; q < 512; q += 256) {
            int row = q >> 3;
            int c4  = q & 7;
            int node = nbase + row;
            float4 v = (node < N) ? *(const float4*)(x + (size_t)node * F_IN + k0 + c4 * 4)
                                  : make_float4(0.f, 0.f, 0.f, 0.f);
            sX[c4 * 4 + 0][row] = v.x;
            sX[c4 * 4 + 1][row] = v.y;
            sX[c4 * 4 + 2][row] = v.z;
            sX[c4 * 4 + 3][row] = v.w;
        }
        #pragma unroll
        for (int q = tid; q < 512; q += 256) {
            int r  = q >> 4;
            int c4 = q & 15;
            *(float4*)&sW[r][c4 * 4] = *(const float4*)(W1 + (size_t)(k0 + r) * F_HID + c4 * 4);
        }
        __syncthreads();

        #pragma unroll
        for (int k = 0; k < MM1_KC; ++k) {
            float4 xv = *(const float4*)&sX[k][n0];
            float4 wv = *(const float4*)&sW[k][f0];
            acc[0][0] = fmaf(xv.x, wv.x, acc[0][0]); acc[0][1] = fmaf(xv.x, wv.y, acc[0][1]);
            acc[0][2] = fmaf(xv.x, wv.z, acc[0][2]); acc[0][3] = fmaf(xv.x, wv.w, acc[0][3]);
            acc[1][0] = fmaf(xv.y, wv.x, acc[1][0]); acc[1][1] = fmaf(xv.y, wv.y, acc[1][1]);
            acc[1][2] = fmaf(xv.y, wv.z, acc[1][2]); acc[1][3] = fmaf(xv.y, wv.w, acc[1][3]);
            acc[2][0] = fmaf(xv.z, wv.x, acc[2][0]); acc[2][1] = fmaf(xv.z, wv.y, acc[2][1]);
            acc[2][2] = fmaf(xv.z, wv.z, acc[2][2]); acc[2][3] = fmaf(xv.z, wv.w, acc[2][3]);
            acc[3][0] = fmaf(xv.w, wv.x, acc[3][0]); acc[3][1] = fmaf(xv.w, wv.y, acc[3][1]);
            acc[3][2] = fmaf(xv.w, wv.z, acc[3][2]); acc[3][3] = fmaf(xv.w, wv.w, acc[3][3]);
        }
        __syncthreads();
    }

    #pragma unroll
    for (int i = 0; i < 4; ++i) {
        int node = nbase + n0 + i;
        if (node < N) {
            float din = dinv[node];
            __half2* p = (__half2*)(hs1 + (size_t)node * F_HID + f0);
            p[0] = __floats2half2_rn(acc[i][0] * din, acc[i][1] * din);
            p[1] = __floats2half2_rn(acc[i][2] * din, acc[i][3] * din);
        }
    }
}

// ---------------------------------------------------------------- gather layer 1
// one wave/node, lane=feature; per edge: 1x aligned 128B line (64 fp16), no dinv[s] load.
// acc = (sum_edges hs1[s] + hs1[node]) * din + b1; relu.
__global__ __launch_bounds__(256) void k_agg1(const unsigned* __restrict__ rowptr,
                                              const unsigned* __restrict__ col,
                                              const float* __restrict__ dinv,
                                              const __half* __restrict__ hs1,
                                              const float* __restrict__ b1,
                                              float* __restrict__ agg1, int N) {
    int lane = threadIdx.x & 63;
    int node = blockIdx.x * 4 + (threadIdx.x >> 6);
    if (node >= N) return;
    float din = dinv[node];
    unsigned r0 = rowptr[node], r1 = rowptr[node + 1];
    float acc = __half2float(hs1[(size_t)node * F_HID + lane]);  // self (pre-scaled)
    unsigned e = r0;
    for (; e + 4 <= r1; e += 4) {
        unsigned s0 = col[e], s1 = col[e + 1], s2 = col[e + 2], s3 = col[e + 3];
        float v0 = __half2float(hs1[(size_t)s0 * F_HID + lane]);
        float v1 = __half2float(hs1[(size_t)s1 * F_HID + lane]);
        float v2 = __half2float(hs1[(size_t)s2 * F_HID + lane]);
        float v3 = __half2float(hs1[(size_t)s3 * F_HID + lane]);
        acc += (v0 + v1) + (v2 + v3);
    }
    for (; e < r1; ++e) {
        unsigned s = col[e];
        acc += __half2float(hs1[(size_t)s * F_HID + lane]);
    }
    float v = acc * din + b1[lane];
    agg1[(size_t)node * F_HID + lane] = v > 0.f ? v : 0.f;
}

// ---------------------------------------------------------------- hs2 = (agg1 @ W2) * dinv, fp16, padded stride 64
__global__ __launch_bounds__(320) void k_mm2(const float* __restrict__ a,
                                             const float* __restrict__ W2,
                                             const float* __restrict__ dinv,
                                             __half* __restrict__ hs2, int N) {
    __shared__ float sW[F_HID * F_OUT];
    int tid = threadIdx.x;
    for (int idx = tid; idx < F_HID * F_OUT; idx += 320) sW[idx] = W2[idx];
    __syncthreads();

    int f = tid % F_OUT, r = tid / F_OUT;
    int node = blockIdx.x * 8 + r;
    if (node >= N) return;
    const float* ar = a + (size_t)node * F_HID;
    float acc = 0.f;
    #pragma unroll 8
    for (int k = 0; k < F_HID; ++k) acc = fmaf(ar[k], sW[k * F_OUT + f], acc);
    hs2[(size_t)node * HS2_LD + f] = __float2half(acc * dinv[node]);
}

// ---------------------------------------------------------------- gather layer 2
// one wave/node (grid-stride), lanes 0..39=features; per edge 1x aligned 128B line.
// out = (sum hs2[s] + hs2[node]) * din; fused column sums. (b2 cancels in PairNorm.)
__global__ __launch_bounds__(256) void k_agg2(const unsigned* __restrict__ rowptr,
                                              const unsigned* __restrict__ col,
                                              const float* __restrict__ dinv,
                                              const __half* __restrict__ hs2,
                                              float* __restrict__ out,
                                              float* __restrict__ colsum, int N) {
    __shared__ float part[256];
    int lane = threadIdx.x & 63;
    int wid = threadIdx.x >> 6;
    float cacc = 0.f;
    if (lane < F_OUT) {
        for (int node = blockIdx.x * 4 + wid; node < N; node += gridDim.x * 4) {
            float din = dinv[node];
            unsigned r0 = rowptr[node], r1 = rowptr[node + 1];
            float acc = __half2float(hs2[(size_t)node * HS2_LD + lane]);
            unsigned e = r0;
            for (; e + 4 <= r1; e += 4) {
                unsigned s0 = col[e], s1 = col[e + 1], s2 = col[e + 2], s3 = col[e + 3];
                float v0 = __half2float(hs2[(size_t)s0 * HS2_LD + lane]);
                float v1 = __half2float(hs2[(size_t)s1 * HS2_LD + lane]);
                float v2 = __half2float(hs2[(size_t)s2 * HS2_LD + lane]);
                float v3 = __half2float(hs2[(size_t)s3 * HS2_LD + lane]);
                acc += (v0 + v1) + (v2 + v3);
            }
            for (; e < r1; ++e) {
                unsigned s = col[e];
                acc += __half2float(hs2[(size_t)s * HS2_LD + lane]);
            }
            acc *= din;
            out[(size_t)node * F_OUT + lane] = acc;
            cacc += acc;
        }
    }
    part[threadIdx.x] = cacc;
    __syncthreads();
    if (threadIdx.x < F_OUT) {
        float s = part[threadIdx.x] + part[64 + threadIdx.x] + part[128 + threadIdx.x] + part[192 + threadIdx.x];
        atomicAdd(&colsum[threadIdx.x], s);
    }
}

// ---------------------------------------------------------------- PairNorm-SI + log_softmax
__global__ __launch_bounds__(128) void k_final(float* __restrict__ out,
                                               const float* __restrict__ colsum, int N) {
    __shared__ float sMean[F_OUT];
    if (threadIdx.x < F_OUT) sMean[threadIdx.x] = colsum[threadIdx.x] * (1.0f / (float)N);
    __syncthreads();
    int n = blockIdx.x * blockDim.x + threadIdx.x;
    if (n >= N) return;
    float* row = out + (size_t)n * F_OUT;
    float v[F_OUT];
    float ss = 0.f;
    #pragma unroll
    for (int f = 0; f < F_OUT; ++f) {
        float t = row[f] - sMean[f];
        v[f] = t;
        ss += t * t;
    }
    float scale = 1.0f / sqrtf(ss + 1e-6f);
    float m = -1e30f;
    #pragma unroll
    for (int f = 0; f < F_OUT; ++f) {
        float y = v[f] * scale;
        v[f] = y;
        m = fmaxf(m, y);
    }
    float sum = 0.f;
    #pragma unroll
    for (int f = 0; f < F_OUT; ++f) sum += expf(v[f] - m);
    float lse = logf(sum);
    #pragma unroll
    for (int f = 0; f < F_OUT; ++f) row[f] = v[f] - m - lse;
}

extern "C" void kernel_launch(void* const* d_in, const int* in_sizes, int n_in,
                              void* d_out, int out_size, void* d_ws, size_t ws_size,
                              hipStream_t stream) {
    const float* x  = (const float*)d_in[0];
    const int*   ei = (const int*)d_in[1];   // int32 per harness (verified R1)
    const float* W1 = (const float*)d_in[2];
    const float* b1 = (const float*)d_in[3];
    const float* W2 = (const float*)d_in[4];
    // b2 unused: cancels under PairNorm mean subtraction.
    float* out = (float*)d_out;

    int N = in_sizes[0] / F_IN;
    int E = in_sizes[1] / 2;
    const int* src = ei;
    const int* dst = ei + E;

    // workspace (4-byte words):
    // [degc N][cursor N][colsum 64][rowptr N+1][col E][dinv N][agg1 64N fp32]
    // [hs1 64N fp16 = 32N words][hs2 64N fp16 = 32N words]
    // scan temporaries exscan(N)+bsum(512) alias the agg1 region (written later).
    unsigned* degc   = (unsigned*)d_ws;
    unsigned* cursor = degc + N;
    float*    colsum = (float*)(cursor + N);
    unsigned* rowptr = (unsigned*)(colsum + 64);
    unsigned* col    = rowptr + N + 1;
    float*    dinv   = (float*)(col + E);
    float*    agg1   = dinv + N;
    __half*   hs1    = (__half*)(agg1 + (size_t)64 * N);
    __half*   hs2    = hs1 + (size_t)64 * N;
    unsigned* exscan = (unsigned*)agg1;      // alias, CSR build only
    unsigned* bsum   = exscan + N;

    // zero degc+cursor+colsum (contiguous)
    hipMemsetAsync(d_ws, 0, ((size_t)2 * N + 64) * sizeof(float), stream);

    int nA = (N + 255) / 256;  // 391 for N=100000, <= 512 for k_scanB
    k_deg<<<(E + 255) / 256, 256, 0, stream>>>(dst, degc, E);
    k_scanA<<<nA, 256, 0, stream>>>(degc, exscan, bsum, N);
    k_scanB<<<1, 512, 0, stream>>>(bsum, nA);
    k_scanC<<<nA, 256, 0, stream>>>(degc, exscan, bsum, rowptr, dinv, N, E);
    k_fill<<<(E + 255) / 256, 256, 0, stream>>>(src, dst, rowptr, cursor, col, E);
    k_mm1<<<(N + 63) / 64, 256, 0, stream>>>(x, W1, dinv, hs1, N);
    k_agg1<<<(N + 3) / 4, 256, 0, stream>>>(rowptr, col, dinv, hs1, b1, agg1, N);
    k_mm2<<<(N + 7) / 8, 320, 0, stream>>>(agg1, W2, dinv, hs2, N);
    k_agg2<<<2048, 256, 0, stream>>>(rowptr, col, dinv, hs2, out, colsum, N);
    k_final<<<(N + 127) / 128, 128, 0, stream>>>(out, colsum, N);
}

// Round 5
// 448.616 us; speedup vs baseline: 4.1342x; 1.0271x over previous
//
#include <hip/hip_runtime.h>
#include <hip/hip_fp16.h>
#include <math.h>

#define F_IN  256
#define F_HID 64
#define F_OUT 40
#define HS2_LD 64   // padded fp16 row stride for hs2: 64*2B = one 128B line

// ---------------------------------------------------------------- degree histogram (int)
__global__ void k_deg(const int* __restrict__ dst, unsigned* __restrict__ degc, int E) {
    int i = blockIdx.x * blockDim.x + threadIdx.x;
    if (i < E) atomicAdd(&degc[dst[i]], 1u);
}

// ---------------------------------------------------------------- 3-phase exclusive scan of degc -> rowptr
__global__ __launch_bounds__(256) void k_scanA(const unsigned* __restrict__ degc,
                                               unsigned* __restrict__ exscan,
                                               unsigned* __restrict__ bsum, int N) {
    __shared__ unsigned s[256];
    int tid = threadIdx.x;
    int i = blockIdx.x * 256 + tid;
    unsigned v = (i < N) ? degc[i] : 0u;
    s[tid] = v;
    __syncthreads();
    for (int off = 1; off < 256; off <<= 1) {
        unsigned t = (tid >= off) ? s[tid - off] : 0u;
        __syncthreads();
        s[tid] += t;
        __syncthreads();
    }
    if (i < N) exscan[i] = s[tid] - v;
    if (tid == 255) bsum[blockIdx.x] = s[255];
}

__global__ __launch_bounds__(512) void k_scanB(unsigned* __restrict__ bsum, int nb) {
    __shared__ unsigned s[512];
    int tid = threadIdx.x;
    unsigned v = (tid < nb) ? bsum[tid] : 0u;
    s[tid] = v;
    __syncthreads();
    for (int off = 1; off < 512; off <<= 1) {
        unsigned t = (tid >= off) ? s[tid - off] : 0u;
        __syncthreads();
        s[tid] += t;
        __syncthreads();
    }
    if (tid < nb) bsum[tid] = s[tid] - v;  // exclusive
}

__global__ void k_scanC(const unsigned* __restrict__ degc, const unsigned* __restrict__ exscan,
                        const unsigned* __restrict__ bsum, unsigned* __restrict__ rowptr,
                        float* __restrict__ dinv, int N, int E) {
    int i = blockIdx.x * blockDim.x + threadIdx.x;
    if (i < N) {
        rowptr[i] = exscan[i] + bsum[i >> 8];
        dinv[i] = rsqrtf((float)degc[i] + 1.0f);  // +1 self loop
        if (i == 0) rowptr[N] = (unsigned)E;
    }
}

// bucket fill: col[rowptr[d] + cursor[d]++] = src
__global__ void k_fill(const int* __restrict__ src, const int* __restrict__ dst,
                       const unsigned* __restrict__ rowptr, unsigned* __restrict__ cursor,
                       unsigned* __restrict__ col, int E) {
    int e = blockIdx.x * blockDim.x + threadIdx.x;
    if (e >= E) return;
    int d = dst[e];
    unsigned p = atomicAdd(&cursor[d], 1u);
    col[rowptr[d] + p] = (unsigned)src[e];
}

// ---------------------------------------------------------------- hs1 = (x @ W1) * dinv[node], fp16
#define MM1_KC 32
#define MM1_XP 68
__global__ __launch_bounds__(256) void k_mm1(const float* __restrict__ x,
                                             const float* __restrict__ W1,
                                             const float* __restrict__ dinv,
                                             __half* __restrict__ hs1, int N) {
    __shared__ float sX[MM1_KC][MM1_XP];  // [k][node]
    __shared__ float sW[MM1_KC][F_HID];   // [k][feat]
    int tid = threadIdx.x;
    int nbase = blockIdx.x * 64;
    int n0 = (tid & 15) * 4;
    int f0 = (tid >> 4) * 4;

    float acc[4][4];
    #pragma unroll
    for (int i = 0; i < 4; ++i)
        #pragma unroll
        for (int j = 0; j < 4; ++j) acc[i][j] = 0.f;

    for (int k0 = 0; k0 < F_IN; k0 += MM1_KC) {
        #pragma unroll
        for (int q = tid; q < 512; q += 256) {
            int row = q >> 3;
            int c4  = q & 7;
            int node = nbase + row;
            float4 v = (node < N) ? *(const float4*)(x + (size_t)node * F_IN + k0 + c4 * 4)
                                  : make_float4(0.f, 0.f, 0.f, 0.f);
            sX[c4 * 4 + 0][row] = v.x;
            sX[c4 * 4 + 1][row] = v.y;
            sX[c4 * 4 + 2][row] = v.z;
            sX[c4 * 4 + 3][row] = v.w;
        }
        #pragma unroll
        for (int q = tid; q < 512; q += 256) {
            int r  = q >> 4;
            int c4 = q & 15;
            *(float4*)&sW[r][c4 * 4] = *(const float4*)(W1 + (size_t)(k0 + r) * F_HID + c4 * 4);
        }
        __syncthreads();

        #pragma unroll
        for (int k = 0; k < MM1_KC; ++k) {
            float4 xv = *(const float4*)&sX[k][n0];
            float4 wv = *(const float4*)&sW[k][f0];
            acc[0][0] = fmaf(xv.x, wv.x, acc[0][0]); acc[0][1] = fmaf(xv.x, wv.y, acc[0][1]);
            acc[0][2] = fmaf(xv.x, wv.z, acc[0][2]); acc[0][3] = fmaf(xv.x, wv.w, acc[0][3]);
            acc[1][0] = fmaf(xv.y, wv.x, acc[1][0]); acc[1][1] = fmaf(xv.y, wv.y, acc[1][1]);
            acc[1][2] = fmaf(xv.y, wv.z, acc[1][2]); acc[1][3] = fmaf(xv.y, wv.w, acc[1][3]);
            acc[2][0] = fmaf(xv.z, wv.x, acc[2][0]); acc[2][1] = fmaf(xv.z, wv.y, acc[2][1]);
            acc[2][2] = fmaf(xv.z, wv.z, acc[2][2]); acc[2][3] = fmaf(xv.z, wv.w, acc[2][3]);
            acc[3][0] = fmaf(xv.w, wv.x, acc[3][0]); acc[3][1] = fmaf(xv.w, wv.y, acc[3][1]);
            acc[3][2] = fmaf(xv.w, wv.z, acc[3][2]); acc[3][3] = fmaf(xv.w, wv.w, acc[3][3]);
        }
        __syncthreads();
    }

    #pragma unroll
    for (int i = 0; i < 4; ++i) {
        int node = nbase + n0 + i;
        if (node < N) {
            float din = dinv[node];
            __half2* p = (__half2*)(hs1 + (size_t)node * F_HID + f0);
            p[0] = __floats2half2_rn(acc[i][0] * din, acc[i][1] * din);
            p[1] = __floats2half2_rn(acc[i][2] * din, acc[i][3] * din);
        }
    }
}

// ---------------------------------------------------------------- gather layer 1
// TWO nodes per wave (A,B): 4+4 interleaved gathers = 8 loads in flight.
// All loop bounds wave-uniform (no divergence). Fused self+bias+ReLU.
__global__ __launch_bounds__(256) void k_agg1(const unsigned* __restrict__ rowptr,
                                              const unsigned* __restrict__ col,
                                              const float* __restrict__ dinv,
                                              const __half* __restrict__ hs1,
                                              const float* __restrict__ bias1,
                                              float* __restrict__ agg1, int N) {
    int lane = threadIdx.x & 63;
    int w = blockIdx.x * 4 + (threadIdx.x >> 6);
    int na = 2 * w, nb = 2 * w + 1;
    if (na >= N) return;

    float dinA = dinv[na];
    unsigned aE = rowptr[na], aEnd = rowptr[na + 1];
    float accA = __half2float(hs1[(size_t)na * F_HID + lane]);  // self (pre-scaled)

    bool hasB = (nb < N);
    float dinB = 0.f, accB = 0.f;
    unsigned bE = 0, bEnd = 0;
    if (hasB) {
        dinB = dinv[nb];
        bE = rowptr[nb]; bEnd = rowptr[nb + 1];
        accB = __half2float(hs1[(size_t)nb * F_HID + lane]);
    }

    while (aE + 4 <= aEnd && bE + 4 <= bEnd) {
        unsigned sa0 = col[aE], sa1 = col[aE + 1], sa2 = col[aE + 2], sa3 = col[aE + 3];
        unsigned sb0 = col[bE], sb1 = col[bE + 1], sb2 = col[bE + 2], sb3 = col[bE + 3];
        float va0 = __half2float(hs1[(size_t)sa0 * F_HID + lane]);
        float va1 = __half2float(hs1[(size_t)sa1 * F_HID + lane]);
        float va2 = __half2float(hs1[(size_t)sa2 * F_HID + lane]);
        float va3 = __half2float(hs1[(size_t)sa3 * F_HID + lane]);
        float vb0 = __half2float(hs1[(size_t)sb0 * F_HID + lane]);
        float vb1 = __half2float(hs1[(size_t)sb1 * F_HID + lane]);
        float vb2 = __half2float(hs1[(size_t)sb2 * F_HID + lane]);
        float vb3 = __half2float(hs1[(size_t)sb3 * F_HID + lane]);
        accA += (va0 + va1) + (va2 + va3);
        accB += (vb0 + vb1) + (vb2 + vb3);
        aE += 4; bE += 4;
    }
    while (aE + 4 <= aEnd) {
        unsigned s0 = col[aE], s1 = col[aE + 1], s2 = col[aE + 2], s3 = col[aE + 3];
        float v0 = __half2float(hs1[(size_t)s0 * F_HID + lane]);
        float v1 = __half2float(hs1[(size_t)s1 * F_HID + lane]);
        float v2 = __half2float(hs1[(size_t)s2 * F_HID + lane]);
        float v3 = __half2float(hs1[(size_t)s3 * F_HID + lane]);
        accA += (v0 + v1) + (v2 + v3);
        aE += 4;
    }
    while (bE + 4 <= bEnd) {
        unsigned s0 = col[bE], s1 = col[bE + 1], s2 = col[bE + 2], s3 = col[bE + 3];
        float v0 = __half2float(hs1[(size_t)s0 * F_HID + lane]);
        float v1 = __half2float(hs1[(size_t)s1 * F_HID + lane]);
        float v2 = __half2float(hs1[(size_t)s2 * F_HID + lane]);
        float v3 = __half2float(hs1[(size_t)s3 * F_HID + lane]);
        accB += (v0 + v1) + (v2 + v3);
        bE += 4;
    }
    while (aE < aEnd && bE < bEnd) {
        unsigned sa = col[aE], sb = col[bE];
        accA += __half2float(hs1[(size_t)sa * F_HID + lane]);
        accB += __half2float(hs1[(size_t)sb * F_HID + lane]);
        ++aE; ++bE;
    }
    while (aE < aEnd) { accA += __half2float(hs1[(size_t)col[aE] * F_HID + lane]); ++aE; }
    while (bE < bEnd) { accB += __half2float(hs1[(size_t)col[bE] * F_HID + lane]); ++bE; }

    float bv = bias1[lane];
    float vA = accA * dinA + bv;
    agg1[(size_t)na * F_HID + lane] = vA > 0.f ? vA : 0.f;
    if (hasB) {
        float vB = accB * dinB + bv;
        agg1[(size_t)nb * F_HID + lane] = vB > 0.f ? vB : 0.f;
    }
}

// ---------------------------------------------------------------- hs2 = (agg1 @ W2) * dinv, fp16, padded stride 64
__global__ __launch_bounds__(320) void k_mm2(const float* __restrict__ a,
                                             const float* __restrict__ W2,
                                             const float* __restrict__ dinv,
                                             __half* __restrict__ hs2, int N) {
    __shared__ float sW[F_HID * F_OUT];
    int tid = threadIdx.x;
    for (int idx = tid; idx < F_HID * F_OUT; idx += 320) sW[idx] = W2[idx];
    __syncthreads();

    int f = tid % F_OUT, r = tid / F_OUT;
    int node = blockIdx.x * 8 + r;
    if (node >= N) return;
    const float* ar = a + (size_t)node * F_HID;
    float acc = 0.f;
    #pragma unroll 8
    for (int k = 0; k < F_HID; ++k) acc = fmaf(ar[k], sW[k * F_OUT + f], acc);
    hs2[(size_t)node * HS2_LD + f] = __float2half(acc * dinv[node]);
}

// ---------------------------------------------------------------- gather layer 2
// TWO nodes per wave, grid-stride over wave-pairs; lanes 0..39 = features.
// Fused self-loop + column sums. (b2 cancels in PairNorm.)
__global__ __launch_bounds__(256) void k_agg2(const unsigned* __restrict__ rowptr,
                                              const unsigned* __restrict__ col,
                                              const float* __restrict__ dinv,
                                              const __half* __restrict__ hs2,
                                              float* __restrict__ out,
                                              float* __restrict__ colsum, int N) {
    __shared__ float part[256];
    int lane = threadIdx.x & 63;
    int wid = threadIdx.x >> 6;
    int nwaves = gridDim.x * 4;
    float cacc = 0.f;
    if (lane < F_OUT) {
        for (int w = blockIdx.x * 4 + wid; 2 * w < N; w += nwaves) {
            int na = 2 * w, nb = 2 * w + 1;
            float dinA = dinv[na];
            unsigned aE = rowptr[na], aEnd = rowptr[na + 1];
            float accA = __half2float(hs2[(size_t)na * HS2_LD + lane]);
            bool hasB = (nb < N);
            float dinB = 0.f, accB = 0.f;
            unsigned bE = 0, bEnd = 0;
            if (hasB) {
                dinB = dinv[nb];
                bE = rowptr[nb]; bEnd = rowptr[nb + 1];
                accB = __half2float(hs2[(size_t)nb * HS2_LD + lane]);
            }

            while (aE + 4 <= aEnd && bE + 4 <= bEnd) {
                unsigned sa0 = col[aE], sa1 = col[aE + 1], sa2 = col[aE + 2], sa3 = col[aE + 3];
                unsigned sb0 = col[bE], sb1 = col[bE + 1], sb2 = col[bE + 2], sb3 = col[bE + 3];
                float va0 = __half2float(hs2[(size_t)sa0 * HS2_LD + lane]);
                float va1 = __half2float(hs2[(size_t)sa1 * HS2_LD + lane]);
                float va2 = __half2float(hs2[(size_t)sa2 * HS2_LD + lane]);
                float va3 = __half2float(hs2[(size_t)sa3 * HS2_LD + lane]);
                float vb0 = __half2float(hs2[(size_t)sb0 * HS2_LD + lane]);
                float vb1 = __half2float(hs2[(size_t)sb1 * HS2_LD + lane]);
                float vb2 = __half2float(hs2[(size_t)sb2 * HS2_LD + lane]);
                float vb3 = __half2float(hs2[(size_t)sb3 * HS2_LD + lane]);
                accA += (va0 + va1) + (va2 + va3);
                accB += (vb0 + vb1) + (vb2 + vb3);
                aE += 4; bE += 4;
            }
            while (aE + 4 <= aEnd) {
                unsigned s0 = col[aE], s1 = col[aE + 1], s2 = col[aE + 2], s3 = col[aE + 3];
                float v0 = __half2float(hs2[(size_t)s0 * HS2_LD + lane]);
                float v1 = __half2float(hs2[(size_t)s1 * HS2_LD + lane]);
                float v2 = __half2float(hs2[(size_t)s2 * HS2_LD + lane]);
                float v3 = __half2float(hs2[(size_t)s3 * HS2_LD + lane]);
                accA += (v0 + v1) + (v2 + v3);
                aE += 4;
            }
            while (bE + 4 <= bEnd) {
                unsigned s0 = col[bE], s1 = col[bE + 1], s2 = col[bE + 2], s3 = col[bE + 3];
                float v0 = __half2float(hs2[(size_t)s0 * HS2_LD + lane]);
                float v1 = __half2float(hs2[(size_t)s1 * HS2_LD + lane]);
                float v2 = __half2float(hs2[(size_t)s2 * HS2_LD + lane]);
                float v3 = __half2float(hs2[(size_t)s3 * HS2_LD + lane]);
                accB += (v0 + v1) + (v2 + v3);
                bE += 4;
            }
            while (aE < aEnd && bE < bEnd) {
                unsigned sa = col[aE], sb = col[bE];
                accA += __half2float(hs2[(size_t)sa * HS2_LD + lane]);
                accB += __half2float(hs2[(size_t)sb * HS2_LD + lane]);
                ++aE; ++bE;
            }
            while (aE < aEnd) { accA += __half2float(hs2[(size_t)col[aE] * HS2_LD + lane]); ++aE; }
            while (bE < bEnd) { accB += __half2float(hs2[(size_t)col[bE] * HS2_LD + lane]); ++bE; }

            accA *= dinA;
            out[(size_t)na * F_OUT + lane] = accA;
            cacc += accA;
            if (hasB) {
                accB *= dinB;
                out[(size_t)nb * F_OUT + lane] = accB;
                cacc += accB;
            }
        }
    }
    part[threadIdx.x] = cacc;
    __syncthreads();
    if (threadIdx.x < F_OUT) {
        float s = part[threadIdx.x] + part[64 + threadIdx.x] + part[128 + threadIdx.x] + part[192 + threadIdx.x];
        atomicAdd(&colsum[threadIdx.x], s);
    }
}

// ---------------------------------------------------------------- PairNorm-SI + log_softmax
__global__ __launch_bounds__(128) void k_final(float* __restrict__ out,
                                               const float* __restrict__ colsum, int N) {
    __shared__ float sMean[F_OUT];
    if (threadIdx.x < F_OUT) sMean[threadIdx.x] = colsum[threadIdx.x] * (1.0f / (float)N);
    __syncthreads();
    int n = blockIdx.x * blockDim.x + threadIdx.x;
    if (n >= N) return;
    float* row = out + (size_t)n * F_OUT;
    float v[F_OUT];
    float ss = 0.f;
    #pragma unroll
    for (int f = 0; f < F_OUT; ++f) {
        float t = row[f] - sMean[f];
        v[f] = t;
        ss += t * t;
    }
    float scale = 1.0f / sqrtf(ss + 1e-6f);
    float m = -1e30f;
    #pragma unroll
    for (int f = 0; f < F_OUT; ++f) {
        float y = v[f] * scale;
        v[f] = y;
        m = fmaxf(m, y);
    }
    float sum = 0.f;
    #pragma unroll
    for (int f = 0; f < F_OUT; ++f) sum += expf(v[f] - m);
    float lse = logf(sum);
    #pragma unroll
    for (int f = 0; f < F_OUT; ++f) row[f] = v[f] - m - lse;
}

extern "C" void kernel_launch(void* const* d_in, const int* in_sizes, int n_in,
                              void* d_out, int out_size, void* d_ws, size_t ws_size,
                              hipStream_t stream) {
    const float* x  = (const float*)d_in[0];
    const int*   ei = (const int*)d_in[1];   // int32 per harness (verified R1)
    const float* W1 = (const float*)d_in[2];
    const float* b1 = (const float*)d_in[3];
    const float* W2 = (const float*)d_in[4];
    // b2 unused: cancels under PairNorm mean subtraction.
    float* out = (float*)d_out;

    int N = in_sizes[0] / F_IN;
    int E = in_sizes[1] / 2;
    const int* src = ei;
    const int* dst = ei + E;

    // workspace (4-byte words):
    // [degc N][cursor N][colsum 64][rowptr N+1][col E][dinv N][agg1 64N fp32]
    // [hs1 64N fp16 = 32N words][hs2 64N fp16 = 32N words]
    // scan temporaries exscan(N)+bsum(512) alias the agg1 region (written later).
    unsigned* degc   = (unsigned*)d_ws;
    unsigned* cursor = degc + N;
    float*    colsum = (float*)(cursor + N);
    unsigned* rowptr = (unsigned*)(colsum + 64);
    unsigned* col    = rowptr + N + 1;
    float*    dinv   = (float*)(col + E);
    float*    agg1   = dinv + N;
    __half*   hs1    = (__half*)(agg1 + (size_t)64 * N);
    __half*   hs2    = hs1 + (size_t)64 * N;
    unsigned* exscan = (unsigned*)agg1;      // alias, CSR build only
    unsigned* bsum   = exscan + N;

    // zero degc+cursor+colsum (contiguous)
    hipMemsetAsync(d_ws, 0, ((size_t)2 * N + 64) * sizeof(float), stream);

    int nA = (N + 255) / 256;  // 391 for N=100000, <= 512 for k_scanB
    k_deg<<<(E + 255) / 256, 256, 0, stream>>>(dst, degc, E);
    k_scanA<<<nA, 256, 0, stream>>>(degc, exscan, bsum, N);
    k_scanB<<<1, 512, 0, stream>>>(bsum, nA);
    k_scanC<<<nA, 256, 0, stream>>>(degc, exscan, bsum, rowptr, dinv, N, E);
    k_fill<<<(E + 255) / 256, 256, 0, stream>>>(src, dst, rowptr, cursor, col, E);
    k_mm1<<<(N + 63) / 64, 256, 0, stream>>>(x, W1, dinv, hs1, N);
    int waves1 = (N + 1) / 2;
    k_agg1<<<(waves1 + 3) / 4, 256, 0, stream>>>(rowptr, col, dinv, hs1, b1, agg1, N);
    k_mm2<<<(N + 7) / 8, 320, 0, stream>>>(agg1, W2, dinv, hs2, N);
    k_agg2<<<2048, 256, 0, stream>>>(rowptr, col, dinv, hs2, out, colsum, N);
    k_final<<<(N + 127) / 128, 128, 0, stream>>>(out, colsum, N);
}

// Round 6
// 443.513 us; speedup vs baseline: 4.1818x; 1.0115x over previous
//
#include <hip/hip_runtime.h>
#include <hip/hip_fp16.h>
#include <math.h>

#define F_IN  256
#define F_HID 64
#define F_OUT 40
#define HS2_LD 64   // padded fp16 row stride for hs2: 64*2B = one 128B line

typedef _Float16 h8 __attribute__((ext_vector_type(8)));
typedef _Float16 h4 __attribute__((ext_vector_type(4)));
typedef float f4 __attribute__((ext_vector_type(4)));

// ---------------------------------------------------------------- degree histogram (int)
__global__ void k_deg(const int* __restrict__ dst, unsigned* __restrict__ degc, int E) {
    int i = blockIdx.x * blockDim.x + threadIdx.x;
    if (i < E) atomicAdd(&degc[dst[i]], 1u);
}

// ---------------------------------------------------------------- 3-phase exclusive scan of degc -> rowptr
__global__ __launch_bounds__(256) void k_scanA(const unsigned* __restrict__ degc,
                                               unsigned* __restrict__ exscan,
                                               unsigned* __restrict__ bsum, int N) {
    __shared__ unsigned s[256];
    int tid = threadIdx.x;
    int i = blockIdx.x * 256 + tid;
    unsigned v = (i < N) ? degc[i] : 0u;
    s[tid] = v;
    __syncthreads();
    for (int off = 1; off < 256; off <<= 1) {
        unsigned t = (tid >= off) ? s[tid - off] : 0u;
        __syncthreads();
        s[tid] += t;
        __syncthreads();
    }
    if (i < N) exscan[i] = s[tid] - v;
    if (tid == 255) bsum[blockIdx.x] = s[255];
}

__global__ __launch_bounds__(512) void k_scanB(unsigned* __restrict__ bsum, int nb) {
    __shared__ unsigned s[512];
    int tid = threadIdx.x;
    unsigned v = (tid < nb) ? bsum[tid] : 0u;
    s[tid] = v;
    __syncthreads();
    for (int off = 1; off < 512; off <<= 1) {
        unsigned t = (tid >= off) ? s[tid - off] : 0u;
        __syncthreads();
        s[tid] += t;
        __syncthreads();
    }
    if (tid < nb) bsum[tid] = s[tid] - v;  // exclusive
}

__global__ void k_scanC(const unsigned* __restrict__ degc, const unsigned* __restrict__ exscan,
                        const unsigned* __restrict__ bsum, unsigned* __restrict__ rowptr,
                        float* __restrict__ dinv, int N, int E) {
    int i = blockIdx.x * blockDim.x + threadIdx.x;
    if (i < N) {
        rowptr[i] = exscan[i] + bsum[i >> 8];
        dinv[i] = rsqrtf((float)degc[i] + 1.0f);  // +1 self loop
        if (i == 0) rowptr[N] = (unsigned)E;
    }
}

// bucket fill: col[rowptr[d] + cursor[d]++] = src
__global__ void k_fill(const int* __restrict__ src, const int* __restrict__ dst,
                       const unsigned* __restrict__ rowptr, unsigned* __restrict__ cursor,
                       unsigned* __restrict__ col, int E) {
    int e = blockIdx.x * blockDim.x + threadIdx.x;
    if (e >= E) return;
    int d = dst[e];
    unsigned p = atomicAdd(&cursor[d], 1u);
    col[rowptr[d] + p] = (unsigned)src[e];
}

// ---------------------------------------------------------------- W1 [256,64] -> Wt fp16 [n][k] (n-major)
__global__ void k_wt(const float* __restrict__ W1, __half* __restrict__ Wt) {
    int i = blockIdx.x * 256 + threadIdx.x;  // 16384
    int k = i >> 6, n = i & 63;
    Wt[n * 256 + k] = __float2half(W1[i]);
}

// ---------------------------------------------------------------- hs1 = (x @ W1) * dinv, fp16, via MFMA
// 64 nodes x 64 feats per block; 4 waves, wave w owns n-range [16w,16w+16).
// B-fragments (W1) preloaded to VGPRs from global Wt; x staged fp32->fp16 in LDS,
// K-chunks of 128, padded row stride 136 halfs.
#define XS 136
__global__ __launch_bounds__(256) void k_mm1(const float* __restrict__ x,
                                             const __half* __restrict__ Wth,
                                             const float* __restrict__ dinv,
                                             __half* __restrict__ hs1o, int N) {
    __shared__ _Float16 sX[64 * XS];  // 17408 B
    const _Float16* Wt = (const _Float16*)Wth;
    _Float16* hs1 = (_Float16*)hs1o;
    int tid = threadIdx.x;
    int lane = tid & 63;
    int wv = tid >> 6;        // ntile
    int m15 = lane & 15;
    int q = lane >> 4;        // quad
    int nbase = blockIdx.x * 64;

    // preload all 8 B-frags: B[k=q*8+j][n=wv*16+m15]
    h8 bf[8];
    #pragma unroll
    for (int kt = 0; kt < 8; ++kt)
        bf[kt] = *(const h8*)(Wt + (wv * 16 + m15) * 256 + kt * 32 + q * 8);

    f4 acc[4];
    #pragma unroll
    for (int mt = 0; mt < 4; ++mt) acc[mt] = (f4){0.f, 0.f, 0.f, 0.f};

    #pragma unroll
    for (int c = 0; c < 2; ++c) {
        // stage 64 nodes x 128 k, coalesced float4 reads, fp16 LDS rows
        #pragma unroll
        for (int p = 0; p < 8; ++p) {
            int idx = p * 256 + tid;
            int row = idx >> 5;
            int c4  = idx & 31;
            int node = nbase + row;
            float4 v = (node < N) ? *(const float4*)(x + (size_t)node * F_IN + c * 128 + c4 * 4)
                                  : make_float4(0.f, 0.f, 0.f, 0.f);
            h4 hv = { (_Float16)v.x, (_Float16)v.y, (_Float16)v.z, (_Float16)v.w };
            *(h4*)&sX[row * XS + c4 * 4] = hv;
        }
        __syncthreads();
        #pragma unroll
        for (int kt2 = 0; kt2 < 4; ++kt2) {
            #pragma unroll
            for (int mt = 0; mt < 4; ++mt) {
                h8 a = *(const h8*)&sX[(mt * 16 + m15) * XS + kt2 * 32 + q * 8];
                acc[mt] = __builtin_amdgcn_mfma_f32_16x16x32_f16(a, bf[c * 4 + kt2], acc[mt], 0, 0, 0);
            }
        }
        __syncthreads();
    }

    // D: row(node) = mt*16 + q*4 + r, col(feat) = wv*16 + m15
    #pragma unroll
    for (int mt = 0; mt < 4; ++mt) {
        #pragma unroll
        for (int r = 0; r < 4; ++r) {
            int node = nbase + mt * 16 + q * 4 + r;
            if (node < N) {
                float din = dinv[node];
                hs1[(size_t)node * F_HID + wv * 16 + m15] = (_Float16)(acc[mt][r] * din);
            }
        }
    }
}

// ---------------------------------------------------------------- gather layer 1
// TWO nodes per wave (A,B): 4+4 interleaved gathers = 8 loads in flight.
__global__ __launch_bounds__(256) void k_agg1(const unsigned* __restrict__ rowptr,
                                              const unsigned* __restrict__ col,
                                              const float* __restrict__ dinv,
                                              const __half* __restrict__ hs1,
                                              const float* __restrict__ bias1,
                                              float* __restrict__ agg1, int N) {
    int lane = threadIdx.x & 63;
    int w = blockIdx.x * 4 + (threadIdx.x >> 6);
    int na = 2 * w, nb = 2 * w + 1;
    if (na >= N) return;

    float dinA = dinv[na];
    unsigned aE = rowptr[na], aEnd = rowptr[na + 1];
    float accA = __half2float(hs1[(size_t)na * F_HID + lane]);  // self (pre-scaled)

    bool hasB = (nb < N);
    float dinB = 0.f, accB = 0.f;
    unsigned bE = 0, bEnd = 0;
    if (hasB) {
        dinB = dinv[nb];
        bE = rowptr[nb]; bEnd = rowptr[nb + 1];
        accB = __half2float(hs1[(size_t)nb * F_HID + lane]);
    }

    while (aE + 4 <= aEnd && bE + 4 <= bEnd) {
        unsigned sa0 = col[aE], sa1 = col[aE + 1], sa2 = col[aE + 2], sa3 = col[aE + 3];
        unsigned sb0 = col[bE], sb1 = col[bE + 1], sb2 = col[bE + 2], sb3 = col[bE + 3];
        float va0 = __half2float(hs1[(size_t)sa0 * F_HID + lane]);
        float va1 = __half2float(hs1[(size_t)sa1 * F_HID + lane]);
        float va2 = __half2float(hs1[(size_t)sa2 * F_HID + lane]);
        float va3 = __half2float(hs1[(size_t)sa3 * F_HID + lane]);
        float vb0 = __half2float(hs1[(size_t)sb0 * F_HID + lane]);
        float vb1 = __half2float(hs1[(size_t)sb1 * F_HID + lane]);
        float vb2 = __half2float(hs1[(size_t)sb2 * F_HID + lane]);
        float vb3 = __half2float(hs1[(size_t)sb3 * F_HID + lane]);
        accA += (va0 + va1) + (va2 + va3);
        accB += (vb0 + vb1) + (vb2 + vb3);
        aE += 4; bE += 4;
    }
    while (aE + 4 <= aEnd) {
        unsigned s0 = col[aE], s1 = col[aE + 1], s2 = col[aE + 2], s3 = col[aE + 3];
        float v0 = __half2float(hs1[(size_t)s0 * F_HID + lane]);
        float v1 = __half2float(hs1[(size_t)s1 * F_HID + lane]);
        float v2 = __half2float(hs1[(size_t)s2 * F_HID + lane]);
        float v3 = __half2float(hs1[(size_t)s3 * F_HID + lane]);
        accA += (v0 + v1) + (v2 + v3);
        aE += 4;
    }
    while (bE + 4 <= bEnd) {
        unsigned s0 = col[bE], s1 = col[bE + 1], s2 = col[bE + 2], s3 = col[bE + 3];
        float v0 = __half2float(hs1[(size_t)s0 * F_HID + lane]);
        float v1 = __half2float(hs1[(size_t)s1 * F_HID + lane]);
        float v2 = __half2float(hs1[(size_t)s2 * F_HID + lane]);
        float v3 = __half2float(hs1[(size_t)s3 * F_HID + lane]);
        accB += (v0 + v1) + (v2 + v3);
        bE += 4;
    }
    while (aE < aEnd && bE < bEnd) {
        unsigned sa = col[aE], sb = col[bE];
        accA += __half2float(hs1[(size_t)sa * F_HID + lane]);
        accB += __half2float(hs1[(size_t)sb * F_HID + lane]);
        ++aE; ++bE;
    }
    while (aE < aEnd) { accA += __half2float(hs1[(size_t)col[aE] * F_HID + lane]); ++aE; }
    while (bE < bEnd) { accB += __half2float(hs1[(size_t)col[bE] * F_HID + lane]); ++bE; }

    float bv = bias1[lane];
    float vA = accA * dinA + bv;
    agg1[(size_t)na * F_HID + lane] = vA > 0.f ? vA : 0.f;
    if (hasB) {
        float vB = accB * dinB + bv;
        agg1[(size_t)nb * F_HID + lane] = vB > 0.f ? vB : 0.f;
    }
}

// ---------------------------------------------------------------- hs2 = (agg1 @ W2) * dinv, fp16, padded stride 64
__global__ __launch_bounds__(320) void k_mm2(const float* __restrict__ a,
                                             const float* __restrict__ W2,
                                             const float* __restrict__ dinv,
                                             __half* __restrict__ hs2, int N) {
    __shared__ float sW[F_HID * F_OUT];
    int tid = threadIdx.x;
    for (int idx = tid; idx < F_HID * F_OUT; idx += 320) sW[idx] = W2[idx];
    __syncthreads();

    int f = tid % F_OUT, r = tid / F_OUT;
    int node = blockIdx.x * 8 + r;
    if (node >= N) return;
    const float* ar = a + (size_t)node * F_HID;
    float acc = 0.f;
    #pragma unroll 8
    for (int k = 0; k < F_HID; ++k) acc = fmaf(ar[k], sW[k * F_OUT + f], acc);
    hs2[(size_t)node * HS2_LD + f] = __float2half(acc * dinv[node]);
}

// ---------------------------------------------------------------- gather layer 2
// TWO nodes per wave, grid-stride; lanes 0..39 = features; fused self + column sums.
__global__ __launch_bounds__(256) void k_agg2(const unsigned* __restrict__ rowptr,
                                              const unsigned* __restrict__ col,
                                              const float* __restrict__ dinv,
                                              const __half* __restrict__ hs2,
                                              float* __restrict__ out,
                                              float* __restrict__ colsum, int N) {
    __shared__ float part[256];
    int lane = threadIdx.x & 63;
    int wid = threadIdx.x >> 6;
    int nwaves = gridDim.x * 4;
    float cacc = 0.f;
    if (lane < F_OUT) {
        for (int w = blockIdx.x * 4 + wid; 2 * w < N; w += nwaves) {
            int na = 2 * w, nb = 2 * w + 1;
            float dinA = dinv[na];
            unsigned aE = rowptr[na], aEnd = rowptr[na + 1];
            float accA = __half2float(hs2[(size_t)na * HS2_LD + lane]);
            bool hasB = (nb < N);
            float dinB = 0.f, accB = 0.f;
            unsigned bE = 0, bEnd = 0;
            if (hasB) {
                dinB = dinv[nb];
                bE = rowptr[nb]; bEnd = rowptr[nb + 1];
                accB = __half2float(hs2[(size_t)nb * HS2_LD + lane]);
            }

            while (aE + 4 <= aEnd && bE + 4 <= bEnd) {
                unsigned sa0 = col[aE], sa1 = col[aE + 1], sa2 = col[aE + 2], sa3 = col[aE + 3];
                unsigned sb0 = col[bE], sb1 = col[bE + 1], sb2 = col[bE + 2], sb3 = col[bE + 3];
                float va0 = __half2float(hs2[(size_t)sa0 * HS2_LD + lane]);
                float va1 = __half2float(hs2[(size_t)sa1 * HS2_LD + lane]);
                float va2 = __half2float(hs2[(size_t)sa2 * HS2_LD + lane]);
                float va3 = __half2float(hs2[(size_t)sa3 * HS2_LD + lane]);
                float vb0 = __half2float(hs2[(size_t)sb0 * HS2_LD + lane]);
                float vb1 = __half2float(hs2[(size_t)sb1 * HS2_LD + lane]);
                float vb2 = __half2float(hs2[(size_t)sb2 * HS2_LD + lane]);
                float vb3 = __half2float(hs2[(size_t)sb3 * HS2_LD + lane]);
                accA += (va0 + va1) + (va2 + va3);
                accB += (vb0 + vb1) + (vb2 + vb3);
                aE += 4; bE += 4;
            }
            while (aE + 4 <= aEnd) {
                unsigned s0 = col[aE], s1 = col[aE + 1], s2 = col[aE + 2], s3 = col[aE + 3];
                float v0 = __half2float(hs2[(size_t)s0 * HS2_LD + lane]);
                float v1 = __half2float(hs2[(size_t)s1 * HS2_LD + lane]);
                float v2 = __half2float(hs2[(size_t)s2 * HS2_LD + lane]);
                float v3 = __half2float(hs2[(size_t)s3 * HS2_LD + lane]);
                accA += (v0 + v1) + (v2 + v3);
                aE += 4;
            }
            while (bE + 4 <= bEnd) {
                unsigned s0 = col[bE], s1 = col[bE + 1], s2 = col[bE + 2], s3 = col[bE + 3];
                float v0 = __half2float(hs2[(size_t)s0 * HS2_LD + lane]);
                float v1 = __half2float(hs2[(size_t)s1 * HS2_LD + lane]);
                float v2 = __half2float(hs2[(size_t)s2 * HS2_LD + lane]);
                float v3 = __half2float(hs2[(size_t)s3 * HS2_LD + lane]);
                accB += (v0 + v1) + (v2 + v3);
                bE += 4;
            }
            while (aE < aEnd && bE < bEnd) {
                unsigned sa = col[aE], sb = col[bE];
                accA += __half2float(hs2[(size_t)sa * HS2_LD + lane]);
                accB += __half2float(hs2[(size_t)sb * HS2_LD + lane]);
                ++aE; ++bE;
            }
            while (aE < aEnd) { accA += __half2float(hs2[(size_t)col[aE] * HS2_LD + lane]); ++aE; }
            while (bE < bEnd) { accB += __half2float(hs2[(size_t)col[bE] * HS2_LD + lane]); ++bE; }

            accA *= dinA;
            out[(size_t)na * F_OUT + lane] = accA;
            cacc += accA;
            if (hasB) {
                accB *= dinB;
                out[(size_t)nb * F_OUT + lane] = accB;
                cacc += accB;
            }
        }
    }
    part[threadIdx.x] = cacc;
    __syncthreads();
    if (threadIdx.x < F_OUT) {
        float s = part[threadIdx.x] + part[64 + threadIdx.x] + part[128 + threadIdx.x] + part[192 + threadIdx.x];
        atomicAdd(&colsum[threadIdx.x], s);
    }
}

// ---------------------------------------------------------------- PairNorm-SI + log_softmax
__global__ __launch_bounds__(128) void k_final(float* __restrict__ out,
                                               const float* __restrict__ colsum, int N) {
    __shared__ float sMean[F_OUT];
    if (threadIdx.x < F_OUT) sMean[threadIdx.x] = colsum[threadIdx.x] * (1.0f / (float)N);
    __syncthreads();
    int n = blockIdx.x * blockDim.x + threadIdx.x;
    if (n >= N) return;
    float* row = out + (size_t)n * F_OUT;
    float v[F_OUT];
    float ss = 0.f;
    #pragma unroll
    for (int f = 0; f < F_OUT; ++f) {
        float t = row[f] - sMean[f];
        v[f] = t;
        ss += t * t;
    }
    float scale = 1.0f / sqrtf(ss + 1e-6f);
    float m = -1e30f;
    #pragma unroll
    for (int f = 0; f < F_OUT; ++f) {
        float y = v[f] * scale;
        v[f] = y;
        m = fmaxf(m, y);
    }
    float sum = 0.f;
    #pragma unroll
    for (int f = 0; f < F_OUT; ++f) sum += expf(v[f] - m);
    float lse = logf(sum);
    #pragma unroll
    for (int f = 0; f < F_OUT; ++f) row[f] = v[f] - m - lse;
}

extern "C" void kernel_launch(void* const* d_in, const int* in_sizes, int n_in,
                              void* d_out, int out_size, void* d_ws, size_t ws_size,
                              hipStream_t stream) {
    const float* x  = (const float*)d_in[0];
    const int*   ei = (const int*)d_in[1];   // int32 per harness (verified R1)
    const float* W1 = (const float*)d_in[2];
    const float* b1 = (const float*)d_in[3];
    const float* W2 = (const float*)d_in[4];
    // b2 unused: cancels under PairNorm mean subtraction.
    float* out = (float*)d_out;

    int N = in_sizes[0] / F_IN;
    int E = in_sizes[1] / 2;
    const int* src = ei;
    const int* dst = ei + E;

    // workspace (4-byte words):
    // [degc N][cursor N][colsum 64][rowptr N+1][col E][dinv N][agg1 64N fp32]
    // [hs1 64N fp16 = 32N words][hs2 64N fp16][Wt 16384 fp16 = 8192 words]
    // scan temporaries exscan(N)+bsum(512) alias the agg1 region.
    unsigned* degc   = (unsigned*)d_ws;
    unsigned* cursor = degc + N;
    float*    colsum = (float*)(cursor + N);
    unsigned* rowptr = (unsigned*)(colsum + 64);
    unsigned* col    = rowptr + N + 1;
    float*    dinv   = (float*)(col + E);
    float*    agg1   = dinv + N;
    __half*   hs1    = (__half*)(agg1 + (size_t)64 * N);
    __half*   hs2    = hs1 + (size_t)64 * N;
    __half*   Wt     = hs2 + (size_t)64 * N;
    unsigned* exscan = (unsigned*)agg1;      // alias, CSR build only
    unsigned* bsum   = exscan + N;

    // zero degc+cursor+colsum (contiguous)
    hipMemsetAsync(d_ws, 0, ((size_t)2 * N + 64) * sizeof(float), stream);

    int nA = (N + 255) / 256;  // 391 for N=100000, <= 512 for k_scanB
    k_deg<<<(E + 255) / 256, 256, 0, stream>>>(dst, degc, E);
    k_scanA<<<nA, 256, 0, stream>>>(degc, exscan, bsum, N);
    k_scanB<<<1, 512, 0, stream>>>(bsum, nA);
    k_scanC<<<nA, 256, 0, stream>>>(degc, exscan, bsum, rowptr, dinv, N, E);
    k_fill<<<(E + 255) / 256, 256, 0, stream>>>(src, dst, rowptr, cursor, col, E);
    k_wt<<<64, 256, 0, stream>>>(W1, Wt);
    k_mm1<<<(N + 63) / 64, 256, 0, stream>>>(x, Wt, dinv, hs1, N);
    int waves1 = (N + 1) / 2;
    k_agg1<<<(waves1 + 3) / 4, 256, 0, stream>>>(rowptr, col, dinv, hs1, b1, agg1, N);
    k_mm2<<<(N + 7) / 8, 320, 0, stream>>>(agg1, W2, dinv, hs2, N);
    k_agg2<<<2048, 256, 0, stream>>>(rowptr, col, dinv, hs2, out, colsum, N);
    k_final<<<(N + 127) / 128, 128, 0, stream>>>(out, colsum, N);
}